// Round 1
// baseline (284.224 us; speedup 1.0000x reference)
//
#include <hip/hip_runtime.h>
#include <hip/hip_bf16.h>
#include <stdint.h>

#define DEV static __device__ __forceinline__

typedef __attribute__((ext_vector_type(8))) short bf16x8;
typedef __attribute__((ext_vector_type(4))) float f32x4;

DEV void async_ld16(const void* g, void* l) {
  __builtin_amdgcn_global_load_lds(
      (const __attribute__((address_space(1))) void*)g,
      (__attribute__((address_space(3))) void*)l, 16, 0, 0);
}

// ---------------- constants ----------------
#define Bb 16
#define Cc 512
#define Nn 4096   // H*W
#define Kk 32
#define NSPLIT 32 // n-chunks for enc partials

// ---------------- K0a: cast conv_w -> bf16 ----------------
__global__ void k_castw(const float* __restrict__ a, __hip_bfloat16* __restrict__ o) {
  int i = blockIdx.x * 256 + threadIdx.x;
  o[i] = __float2bfloat16(a[i]);
}

// ---------------- K0b: codewords -> bf16 + cw_sq ----------------
__global__ void k_cw(const float* __restrict__ cw, __hip_bfloat16* __restrict__ cwb,
                     float* __restrict__ cwsq) {
  int k = blockIdx.x, lane = threadIdx.x; // 64 lanes
  float s = 0.f;
#pragma unroll
  for (int j = 0; j < 8; ++j) {
    float v = cw[k * Cc + lane * 8 + j];
    cwb[k * Cc + lane * 8 + j] = __float2bfloat16(v);
    s += v * v;
  }
  for (int off = 32; off; off >>= 1) s += __shfl_down(s, off);
  if (lane == 0) cwsq[k] = s;
}

// ---------------- K1: transpose-cast x[b,c,n] -> xT[b,n,c] bf16 ----------------
__global__ __launch_bounds__(256) void k_xpose(const float* __restrict__ x,
                                               __hip_bfloat16* __restrict__ xT) {
  __shared__ float tile[32][33];
  int b = blockIdx.z;
  int n0 = blockIdx.x * 32;
  int c0 = blockIdx.y * 32;
  int tx = threadIdx.x;  // 32
  int ty = threadIdx.y;  // 8
  const float* xp = x + ((size_t)b * Cc * Nn + (size_t)c0 * Nn + n0);
#pragma unroll
  for (int i = 0; i < 32; i += 8)
    tile[ty + i][tx] = xp[(size_t)(ty + i) * Nn + tx];  // [c_local][n_local]
  __syncthreads();
  __hip_bfloat16* xo = xT + ((size_t)b * Nn * Cc + (size_t)n0 * Cc + c0);
#pragma unroll
  for (int i = 0; i < 32; i += 8)
    xo[(size_t)(ty + i) * Cc + tx] = __float2bfloat16(tile[tx][ty + i]);
}

// ---------------- K2: z[b,n,c] = xT . conv_w^T + bias  (bf16 MFMA) ----------------
__global__ __launch_bounds__(256) void k_gemm_z(const __hip_bfloat16* __restrict__ A,
                                                const __hip_bfloat16* __restrict__ Bw,
                                                const float* __restrict__ bias,
                                                __hip_bfloat16* __restrict__ Z) {
  __shared__ __align__(16) __hip_bfloat16 As[128 * 32];
  __shared__ __align__(16) __hip_bfloat16 Bs[128 * 32];
  const int b = blockIdx.z;
  const int n0 = blockIdx.x * 128;
  const int c0 = blockIdx.y * 128;
  const int tid = threadIdx.x;
  const int lane = tid & 63, wid = tid >> 6;
  const int wr = (wid >> 1) * 64, wc = (wid & 1) * 64;
  const __hip_bfloat16* Ab = A + ((size_t)b * Nn + n0) * Cc;
  const __hip_bfloat16* Bbp = Bw + (size_t)c0 * Cc;
  f32x4 acc[4][4] = {};
  for (int kt = 0; kt < 16; ++kt) {
    int k0 = kt * 32;
    __syncthreads();
#pragma unroll
    for (int j = 0; j < 2; ++j) {
      int li = tid + j * 256;
      int row = li >> 2, kc = (li & 3) * 8;
      async_ld16(Ab + (size_t)row * Cc + k0 + kc, (char*)As + li * 16);
      async_ld16(Bbp + (size_t)row * Cc + k0 + kc, (char*)Bs + li * 16);
    }
    __syncthreads();
    bf16x8 af[4], bfv[4];
#pragma unroll
    for (int m = 0; m < 4; ++m)
      af[m] = *(const bf16x8*)&As[(wr + m * 16 + (lane & 15)) * 32 + (lane >> 4) * 8];
#pragma unroll
    for (int nf = 0; nf < 4; ++nf)
      bfv[nf] = *(const bf16x8*)&Bs[(wc + nf * 16 + (lane & 15)) * 32 + (lane >> 4) * 8];
#pragma unroll
    for (int m = 0; m < 4; ++m)
#pragma unroll
      for (int nf = 0; nf < 4; ++nf)
        acc[m][nf] = __builtin_amdgcn_mfma_f32_16x16x32_bf16(af[m], bfv[nf], acc[m][nf], 0, 0, 0);
  }
  __hip_bfloat16* Zb = Z + ((size_t)b * Nn + n0) * Cc + c0;
#pragma unroll
  for (int nf = 0; nf < 4; ++nf) {
    int col = wc + nf * 16 + (lane & 15);
    float bv = bias[c0 + col];
#pragma unroll
    for (int m = 0; m < 4; ++m) {
#pragma unroll
      for (int r = 0; r < 4; ++r) {
        int row = wr + m * 16 + (lane >> 4) * 4 + r;
        Zb[(size_t)row * Cc + col] = __float2bfloat16(acc[m][nf][r] + bv);
      }
    }
  }
}

// ---------------- K3: cross[b,n,k] = z . cw^T (MFMA) + z_sq ----------------
__global__ __launch_bounds__(256) void k_cross(const __hip_bfloat16* __restrict__ Z,
                                               const __hip_bfloat16* __restrict__ CW,
                                               float* __restrict__ cross,
                                               float* __restrict__ zsq) {
  __shared__ __align__(16) __hip_bfloat16 As[128 * 32];
  __shared__ __align__(16) __hip_bfloat16 Bs[32 * 32];
  int b = blockIdx.y;
  int n0 = blockIdx.x * 128;
  int tid = threadIdx.x, lane = tid & 63, wid = tid >> 6;
  const __hip_bfloat16* Ab = Z + ((size_t)b * Nn + n0) * Cc;
  f32x4 acc[2][2] = {};
  float sq = 0.f;
  for (int kt = 0; kt < 16; ++kt) {
    int k0 = kt * 32;
    __syncthreads();
#pragma unroll
    for (int j = 0; j < 2; ++j) {
      int li = tid + j * 256;
      int row = li >> 2, kc = (li & 3) * 8;
      async_ld16(Ab + (size_t)row * Cc + k0 + kc, (char*)As + li * 16);
    }
    if (tid < 128) {
      int row = tid >> 2, kc = (tid & 3) * 8;
      async_ld16(CW + (size_t)row * Cc + k0 + kc, (char*)Bs + tid * 16);
    }
    __syncthreads();
    {  // z_sq partial from staged tile
      int row = tid >> 1, h = (tid & 1) * 16;
      const __hip_bfloat16* p = &As[row * 32 + h];
#pragma unroll
      for (int i = 0; i < 16; ++i) {
        float v = __bfloat162float(p[i]);
        sq += v * v;
      }
    }
    bf16x8 af[2], bfv[2];
#pragma unroll
    for (int m = 0; m < 2; ++m)
      af[m] = *(const bf16x8*)&As[(wid * 32 + m * 16 + (lane & 15)) * 32 + (lane >> 4) * 8];
#pragma unroll
    for (int nf = 0; nf < 2; ++nf)
      bfv[nf] = *(const bf16x8*)&Bs[(nf * 16 + (lane & 15)) * 32 + (lane >> 4) * 8];
#pragma unroll
    for (int m = 0; m < 2; ++m)
#pragma unroll
      for (int nf = 0; nf < 2; ++nf)
        acc[m][nf] = __builtin_amdgcn_mfma_f32_16x16x32_bf16(af[m], bfv[nf], acc[m][nf], 0, 0, 0);
  }
  sq += __shfl_xor(sq, 1);
  if ((tid & 1) == 0) zsq[(size_t)b * Nn + n0 + (tid >> 1)] = sq;
  float* Cb = cross + ((size_t)b * Nn + n0) * Kk;
#pragma unroll
  for (int m = 0; m < 2; ++m)
#pragma unroll
    for (int nf = 0; nf < 2; ++nf) {
      int col = nf * 16 + (lane & 15);
#pragma unroll
      for (int r = 0; r < 4; ++r) {
        int row = wid * 32 + m * 16 + (lane >> 4) * 4 + r;
        Cb[(size_t)row * Kk + col] = acc[m][nf][r];
      }
    }
}

// ---------------- K4: softmax over k (in-place cross->assign) + asum ----------------
__global__ __launch_bounds__(256) void k_softmax(float* __restrict__ crossA,
                                                 const float* __restrict__ zsq,
                                                 const float* __restrict__ scale,
                                                 const float* __restrict__ cwsq,
                                                 float* __restrict__ asum) {
  __shared__ float s_sum[Kk];
  __shared__ float s_scale[Kk], s_cwsq[Kk];
  int tid = threadIdx.x;
  size_t gn = (size_t)blockIdx.x * 256 + tid;
  int b = (int)(gn >> 12);
  if (tid < Kk) {
    s_sum[tid] = 0.f;
    s_scale[tid] = scale[tid];
    s_cwsq[tid] = cwsq[tid];
  }
  __syncthreads();
  float zq = zsq[gn];
  float* p = crossA + gn * Kk;
  float d[Kk];
  const float4* p4 = (const float4*)p;
#pragma unroll
  for (int j = 0; j < 8; ++j) {
    float4 t = p4[j];
    d[4 * j + 0] = t.x; d[4 * j + 1] = t.y; d[4 * j + 2] = t.z; d[4 * j + 3] = t.w;
  }
  float mx = -1e30f;
#pragma unroll
  for (int k = 0; k < Kk; ++k) {
    d[k] = s_scale[k] * (zq - 2.f * d[k] + s_cwsq[k]);
    mx = fmaxf(mx, d[k]);
  }
  float sum = 0.f;
#pragma unroll
  for (int k = 0; k < Kk; ++k) {
    d[k] = __expf(d[k] - mx);
    sum += d[k];
  }
  float inv = 1.f / sum;
  float4* w4 = (float4*)p;
#pragma unroll
  for (int j = 0; j < 8; ++j) {
    float4 t;
    t.x = d[4 * j + 0] * inv; t.y = d[4 * j + 1] * inv;
    t.z = d[4 * j + 2] * inv; t.w = d[4 * j + 3] * inv;
    w4[j] = t;
  }
#pragma unroll
  for (int k = 0; k < Kk; ++k) atomicAdd(&s_sum[k], d[k] * inv);
  __syncthreads();
  if (tid < Kk) atomicAdd(&asum[b * Kk + tid], s_sum[tid]);
}

// ---------------- K5: enc partials: part[s][b][k][c] ----------------
__global__ __launch_bounds__(256) void k_enc_part(const float* __restrict__ assign,
                                                  const __hip_bfloat16* __restrict__ Z,
                                                  float* __restrict__ part) {
  __shared__ float sa[128][Kk];
  int b = blockIdx.z;
  int s = blockIdx.y;
  int c = blockIdx.x * 256 + threadIdx.x;
  int tid = threadIdx.x;
  int n0 = s * 128;
  const float* ap = assign + ((size_t)b * Nn + n0) * Kk;
  for (int i = tid; i < 128 * Kk; i += 256) sa[i >> 5][i & 31] = ap[i];
  __syncthreads();
  float acc[Kk];
#pragma unroll
  for (int k = 0; k < Kk; ++k) acc[k] = 0.f;
  const __hip_bfloat16* zp = Z + ((size_t)b * Nn + n0) * Cc + c;
  for (int n = 0; n < 128; ++n) {
    float zv = __bfloat162float(zp[(size_t)n * Cc]);
    const float4* sp = (const float4*)&sa[n][0];
#pragma unroll
    for (int q = 0; q < 8; ++q) {
      float4 a4 = sp[q];
      acc[4 * q + 0] = fmaf(a4.x, zv, acc[4 * q + 0]);
      acc[4 * q + 1] = fmaf(a4.y, zv, acc[4 * q + 1]);
      acc[4 * q + 2] = fmaf(a4.z, zv, acc[4 * q + 2]);
      acc[4 * q + 3] = fmaf(a4.w, zv, acc[4 * q + 3]);
    }
  }
  float* pp = part + (((size_t)s * Bb + b) * Kk) * Cc + c;
#pragma unroll
  for (int k = 0; k < Kk; ++k) pp[(size_t)k * Cc] = acc[k];
}

// ---------------- K6: reduce partials + BN + relu -> encr[b][k][c] ----------------
__global__ __launch_bounds__(256) void k_enc_bn(const float* __restrict__ part,
                                                const float* __restrict__ asum,
                                                const float* __restrict__ cw,
                                                const float* __restrict__ bn_g,
                                                const float* __restrict__ bn_b,
                                                const float* __restrict__ bn_m,
                                                const float* __restrict__ bn_v,
                                                float* __restrict__ encr) {
  int bk = blockIdx.x;  // b*32+k
  int b = bk >> 5, k = bk & 31;
  int tid = threadIdx.x;
  float g = bn_g[k], bt = bn_b[k], mn = bn_m[k], iv = rsqrtf(bn_v[k] + 1e-5f);
  float as = asum[bk];
  for (int c = tid; c < Cc; c += 256) {
    float e = 0.f;
#pragma unroll
    for (int s = 0; s < NSPLIT; ++s)
      e += part[(((size_t)s * Bb + b) * Kk + k) * Cc + c];
    e -= as * cw[k * Cc + c];
    e = (e - mn) * (iv * g) + bt;
    e = fmaxf(e, 0.f);
    encr[((size_t)b * Kk + k) * Cc + c] = e;
  }
}

// ---------------- K7: mean over k -> encoding_feat (d_out) ----------------
__global__ void k_mean(const float* __restrict__ encr, float* __restrict__ ef) {
  int b = blockIdx.x;
  int c = threadIdx.x;  // 512
  float s = 0.f;
#pragma unroll
  for (int k = 0; k < Kk; ++k) s += encr[((size_t)b * Kk + k) * Cc + c];
  ef[b * Cc + c] = s * (1.f / 32.f);
}

// ---------------- K8: fc + sigmoid -> gamma[b][o] ----------------
__global__ void k_fc(const float* __restrict__ ef, const float* __restrict__ fcw,
                     const float* __restrict__ fcb, float* __restrict__ gamma) {
  int b = blockIdx.x;
  int o = blockIdx.y * 4 + (threadIdx.x >> 6);
  int lane = threadIdx.x & 63;
  const float* w = fcw + (size_t)o * Cc;
  const float* e = ef + b * Cc;
  float s = 0.f;
#pragma unroll
  for (int j = 0; j < 8; ++j) s += e[lane + j * 64] * w[lane + j * 64];
  for (int off = 32; off; off >>= 1) s += __shfl_down(s, off);
  if (lane == 0) gamma[b * Cc + o] = 1.f / (1.f + __expf(-(s + fcb[o])));
}

// ---------------- K9: output = relu(x * (1+gamma)) ----------------
__global__ __launch_bounds__(256) void k_out(const float* __restrict__ x,
                                             const float* __restrict__ gamma,
                                             float* __restrict__ out) {
  size_t total = (size_t)Bb * Cc * Nn / 4;
  for (size_t i = (size_t)blockIdx.x * 256 + threadIdx.x; i < total;
       i += (size_t)gridDim.x * 256) {
    float4 v = ((const float4*)x)[i];
    int bc = (int)(i >> 10);  // 1024 float4 per (b,c)
    float m = 1.f + gamma[bc];
    float4 r;
    r.x = fmaxf(v.x * m, 0.f);
    r.y = fmaxf(v.y * m, 0.f);
    r.z = fmaxf(v.z * m, 0.f);
    r.w = fmaxf(v.w * m, 0.f);
    ((float4*)out)[i] = r;
  }
}

extern "C" void kernel_launch(void* const* d_in, const int* in_sizes, int n_in,
                              void* d_out, int out_size, void* d_ws, size_t ws_size,
                              hipStream_t stream) {
  const float* x = (const float*)d_in[0];
  const float* conv_w = (const float*)d_in[1];
  const float* conv_b = (const float*)d_in[2];
  const float* codewords = (const float*)d_in[3];
  const float* scale = (const float*)d_in[4];
  const float* bn_gamma = (const float*)d_in[5];
  const float* bn_beta = (const float*)d_in[6];
  const float* bn_mean = (const float*)d_in[7];
  const float* bn_var = (const float*)d_in[8];
  const float* fc_w = (const float*)d_in[9];
  const float* fc_b = (const float*)d_in[10];

  float* ef_out = (float*)d_out;            // [16][512]
  float* out = (float*)d_out + Bb * Cc;     // [16][512][4096]

  char* ws = (char*)d_ws;
  size_t off = 0;
  __hip_bfloat16* xT = (__hip_bfloat16*)(ws + off);  // 64 MB (aliased by part later)
  float* part = (float*)(ws + off);                  // 32 MB, reuses xT after GEMM
  off += (size_t)Bb * Nn * Cc * 2;
  __hip_bfloat16* z = (__hip_bfloat16*)(ws + off);   // 64 MB
  off += (size_t)Bb * Nn * Cc * 2;
  float* cross = (float*)(ws + off);                 // 8 MB (assign in-place)
  off += (size_t)Bb * Nn * Kk * 4;
  __hip_bfloat16* wbf = (__hip_bfloat16*)(ws + off);
  off += (size_t)Cc * Cc * 2;
  __hip_bfloat16* cwb = (__hip_bfloat16*)(ws + off);
  off += (size_t)Kk * Cc * 2;
  float* cwsq = (float*)(ws + off);
  off += 512;
  float* zsq = (float*)(ws + off);
  off += (size_t)Bb * Nn * 4;
  float* asum = (float*)(ws + off);
  off += (size_t)Bb * Kk * 4;
  float* encr = (float*)(ws + off);
  off += (size_t)Bb * Kk * Cc * 4;
  float* gamma = (float*)(ws + off);
  off += (size_t)Bb * Cc * 4;
  (void)ws_size; (void)n_in; (void)in_sizes; (void)out_size;

  hipMemsetAsync(asum, 0, Bb * Kk * 4, stream);

  k_castw<<<dim3(Cc * Cc / 256), dim3(256), 0, stream>>>(conv_w, wbf);
  k_cw<<<dim3(Kk), dim3(64), 0, stream>>>(codewords, cwb, cwsq);
  k_xpose<<<dim3(Nn / 32, Cc / 32, Bb), dim3(32, 8), 0, stream>>>(x, xT);
  k_gemm_z<<<dim3(Nn / 128, Cc / 128, Bb), dim3(256), 0, stream>>>(xT, wbf, conv_b, z);
  k_cross<<<dim3(Nn / 128, Bb), dim3(256), 0, stream>>>(z, cwb, cross, zsq);
  k_softmax<<<dim3(Bb * Nn / 256), dim3(256), 0, stream>>>(cross, zsq, scale, cwsq, asum);
  k_enc_part<<<dim3(Cc / 256, NSPLIT, Bb), dim3(256), 0, stream>>>(cross, z, part);
  k_enc_bn<<<dim3(Bb * Kk), dim3(256), 0, stream>>>(part, asum, codewords, bn_gamma, bn_beta,
                                                    bn_mean, bn_var, encr);
  k_mean<<<dim3(Bb), dim3(512), 0, stream>>>(encr, ef_out);
  k_fc<<<dim3(Bb, Cc / 4), dim3(256), 0, stream>>>(ef_out, fc_w, fc_b, gamma);
  k_out<<<dim3(2048), dim3(256), 0, stream>>>(x, gamma, out);
}

// Round 2
// 282.540 us; speedup vs baseline: 1.0060x; 1.0060x over previous
//
#include <hip/hip_runtime.h>
#include <hip/hip_bf16.h>
#include <stdint.h>

#define DEV static __device__ __forceinline__

typedef __attribute__((ext_vector_type(8))) short bf16x8;
typedef __attribute__((ext_vector_type(4))) float f32x4;

DEV void async_ld16(const void* g, void* l) {
  __builtin_amdgcn_global_load_lds(
      (const __attribute__((address_space(1))) void*)g,
      (__attribute__((address_space(3))) void*)l, 16, 0, 0);
}

DEV unsigned short f2bf(float f) {
  union { __hip_bfloat16 h; unsigned short u; } c;
  c.h = __float2bfloat16(f);
  return c.u;
}

// ---------------- constants ----------------
#define Bb 16
#define Cc 512
#define Nn 4096   // H*W
#define Kk 32
#define NSPLIT 32 // n-chunks for enc partials

// ---------------- K0a: cast conv_w -> bf16 ----------------
__global__ void k_castw(const float* __restrict__ a, __hip_bfloat16* __restrict__ o) {
  int i = blockIdx.x * 256 + threadIdx.x;
  o[i] = __float2bfloat16(a[i]);
}

// ---------------- K0b: codewords -> bf16 + cw_sq ----------------
__global__ void k_cw(const float* __restrict__ cw, __hip_bfloat16* __restrict__ cwb,
                     float* __restrict__ cwsq) {
  int k = blockIdx.x, lane = threadIdx.x; // 64 lanes
  float s = 0.f;
#pragma unroll
  for (int j = 0; j < 8; ++j) {
    float v = cw[k * Cc + lane * 8 + j];
    cwb[k * Cc + lane * 8 + j] = __float2bfloat16(v);
    s += v * v;
  }
  for (int off = 32; off; off >>= 1) s += __shfl_down(s, off);
  if (lane == 0) cwsq[k] = s;
}

// ---------------- K2: z[b,n,c] = x^T . conv_w^T + bias (fused transpose-cast MFMA) ----------------
// A-operand (x) is staged per K-step with an in-kernel transpose:
//   global: scalar-coalesced row reads of x[c][n] (64 lanes x 4B = 256B/inst)
//   LDS:    As[128 n][36 pad] shorts; b64 writes of 4 c-elems (4-way bank, 1.58x)
//   frags:  2x ds_read_b64 per 16x16 fragment (8B-aligned; 4-way bank)
__global__ __launch_bounds__(256) void k_gemm_z(const float* __restrict__ X,
                                                const __hip_bfloat16* __restrict__ Bw,
                                                const float* __restrict__ bias,
                                                __hip_bfloat16* __restrict__ Z) {
  constexpr int LDA = 36;  // padded row stride (elements)
  __shared__ __align__(16) unsigned short As[128 * LDA];   // 9216 B
  __shared__ __align__(16) __hip_bfloat16 Bs[128 * 32];    // 8192 B
  const int b = blockIdx.y;
  const int n0 = (blockIdx.x >> 2) * 128;   // c0 fastest: siblings share x-panel via L2/L3
  const int c0 = (blockIdx.x & 3) * 128;
  const int tid = threadIdx.x;
  const int lane = tid & 63, wid = tid >> 6;
  const int wr = (wid >> 1) * 64, wc = (wid & 1) * 64;
  const float* Xb = X + (size_t)b * Cc * Nn + n0;  // row c: Xb[c*Nn + n]
  const __hip_bfloat16* Bbp = Bw + (size_t)c0 * Cc;
  f32x4 acc[4][4] = {};
  for (int kt = 0; kt < 16; ++kt) {
    int k0 = kt * 32;
    __syncthreads();
    // ---- B staging via global_load_lds (unchanged, verified) ----
#pragma unroll
    for (int j = 0; j < 2; ++j) {
      int li = tid + j * 256;
      int row = li >> 2, kc = (li & 3) * 8;
      async_ld16(Bbp + (size_t)row * Cc + k0 + kc, (char*)Bs + li * 16);
    }
    // ---- A staging: fused transpose-cast ----
    // li = tid + 256j covers [0,1024): n = li&127, cg = li>>7 ; elems (c=4cg+i, n)
    float v[4][4];
#pragma unroll
    for (int j = 0; j < 4; ++j) {
      int li = tid + j * 256;
      int n = li & 127, cg = li >> 7;
#pragma unroll
      for (int i = 0; i < 4; ++i)
        v[j][i] = Xb[(size_t)(k0 + cg * 4 + i) * Nn + n];
    }
#pragma unroll
    for (int j = 0; j < 4; ++j) {
      int li = tid + j * 256;
      int n = li & 127, cg = li >> 7;
      ushort4 w;
      w.x = f2bf(v[j][0]);
      w.y = f2bf(v[j][1]);
      w.z = f2bf(v[j][2]);
      w.w = f2bf(v[j][3]);
      *(ushort4*)&As[n * LDA + cg * 4] = w;  // ds_write_b64, transposed layout
    }
    __syncthreads();
    // ---- fragment reads + MFMA ----
    bf16x8 af[4], bfv[4];
#pragma unroll
    for (int m = 0; m < 4; ++m) {
      int row = wr + m * 16 + (lane & 15);
      int base = row * LDA + (lane >> 4) * 8;
      union { ushort4 u2[2]; bf16x8 v8; } t;
      t.u2[0] = *(const ushort4*)&As[base];
      t.u2[1] = *(const ushort4*)&As[base + 4];
      af[m] = t.v8;
    }
#pragma unroll
    for (int nf = 0; nf < 4; ++nf)
      bfv[nf] = *(const bf16x8*)&Bs[(wc + nf * 16 + (lane & 15)) * 32 + (lane >> 4) * 8];
#pragma unroll
    for (int m = 0; m < 4; ++m)
#pragma unroll
      for (int nf = 0; nf < 4; ++nf)
        acc[m][nf] = __builtin_amdgcn_mfma_f32_16x16x32_bf16(af[m], bfv[nf], acc[m][nf], 0, 0, 0);
  }
  __hip_bfloat16* Zb = Z + ((size_t)b * Nn + n0) * Cc + c0;
#pragma unroll
  for (int nf = 0; nf < 4; ++nf) {
    int col = wc + nf * 16 + (lane & 15);
    float bv = bias[c0 + col];
#pragma unroll
    for (int m = 0; m < 4; ++m) {
#pragma unroll
      for (int r = 0; r < 4; ++r) {
        int row = wr + m * 16 + (lane >> 4) * 4 + r;
        Zb[(size_t)row * Cc + col] = __float2bfloat16(acc[m][nf][r] + bv);
      }
    }
  }
}

// ---------------- K3: cross[b,n,k] = z . cw^T (MFMA) + z_sq ----------------
__global__ __launch_bounds__(256) void k_cross(const __hip_bfloat16* __restrict__ Z,
                                               const __hip_bfloat16* __restrict__ CW,
                                               float* __restrict__ cross,
                                               float* __restrict__ zsq) {
  __shared__ __align__(16) __hip_bfloat16 As[128 * 32];
  __shared__ __align__(16) __hip_bfloat16 Bs[32 * 32];
  int b = blockIdx.y;
  int n0 = blockIdx.x * 128;
  int tid = threadIdx.x, lane = tid & 63, wid = tid >> 6;
  const __hip_bfloat16* Ab = Z + ((size_t)b * Nn + n0) * Cc;
  f32x4 acc[2][2] = {};
  float sq = 0.f;
  for (int kt = 0; kt < 16; ++kt) {
    int k0 = kt * 32;
    __syncthreads();
#pragma unroll
    for (int j = 0; j < 2; ++j) {
      int li = tid + j * 256;
      int row = li >> 2, kc = (li & 3) * 8;
      async_ld16(Ab + (size_t)row * Cc + k0 + kc, (char*)As + li * 16);
    }
    if (tid < 128) {
      int row = tid >> 2, kc = (tid & 3) * 8;
      async_ld16(CW + (size_t)row * Cc + k0 + kc, (char*)Bs + tid * 16);
    }
    __syncthreads();
    {  // z_sq partial from staged tile
      int row = tid >> 1, h = (tid & 1) * 16;
      const __hip_bfloat16* p = &As[row * 32 + h];
#pragma unroll
      for (int i = 0; i < 16; ++i) {
        float v = __bfloat162float(p[i]);
        sq += v * v;
      }
    }
    bf16x8 af[2], bfv[2];
#pragma unroll
    for (int m = 0; m < 2; ++m)
      af[m] = *(const bf16x8*)&As[(wid * 32 + m * 16 + (lane & 15)) * 32 + (lane >> 4) * 8];
#pragma unroll
    for (int nf = 0; nf < 2; ++nf)
      bfv[nf] = *(const bf16x8*)&Bs[(nf * 16 + (lane & 15)) * 32 + (lane >> 4) * 8];
#pragma unroll
    for (int m = 0; m < 2; ++m)
#pragma unroll
      for (int nf = 0; nf < 2; ++nf)
        acc[m][nf] = __builtin_amdgcn_mfma_f32_16x16x32_bf16(af[m], bfv[nf], acc[m][nf], 0, 0, 0);
  }
  sq += __shfl_xor(sq, 1);
  if ((tid & 1) == 0) zsq[(size_t)b * Nn + n0 + (tid >> 1)] = sq;
  float* Cb = cross + ((size_t)b * Nn + n0) * Kk;
#pragma unroll
  for (int m = 0; m < 2; ++m)
#pragma unroll
    for (int nf = 0; nf < 2; ++nf) {
      int col = nf * 16 + (lane & 15);
#pragma unroll
      for (int r = 0; r < 4; ++r) {
        int row = wid * 32 + m * 16 + (lane >> 4) * 4 + r;
        Cb[(size_t)row * Kk + col] = acc[m][nf][r];
      }
    }
}

// ---------------- K4: softmax over k (in-place cross->assign) + asum ----------------
__global__ __launch_bounds__(256) void k_softmax(float* __restrict__ crossA,
                                                 const float* __restrict__ zsq,
                                                 const float* __restrict__ scale,
                                                 const float* __restrict__ cwsq,
                                                 float* __restrict__ asum) {
  __shared__ float s_sum[Kk];
  __shared__ float s_scale[Kk], s_cwsq[Kk];
  int tid = threadIdx.x;
  size_t gn = (size_t)blockIdx.x * 256 + tid;
  int b = (int)(gn >> 12);
  if (tid < Kk) {
    s_sum[tid] = 0.f;
    s_scale[tid] = scale[tid];
    s_cwsq[tid] = cwsq[tid];
  }
  __syncthreads();
  float zq = zsq[gn];
  float* p = crossA + gn * Kk;
  float d[Kk];
  const float4* p4 = (const float4*)p;
#pragma unroll
  for (int j = 0; j < 8; ++j) {
    float4 t = p4[j];
    d[4 * j + 0] = t.x; d[4 * j + 1] = t.y; d[4 * j + 2] = t.z; d[4 * j + 3] = t.w;
  }
  float mx = -1e30f;
#pragma unroll
  for (int k = 0; k < Kk; ++k) {
    d[k] = s_scale[k] * (zq - 2.f * d[k] + s_cwsq[k]);
    mx = fmaxf(mx, d[k]);
  }
  float sum = 0.f;
#pragma unroll
  for (int k = 0; k < Kk; ++k) {
    d[k] = __expf(d[k] - mx);
    sum += d[k];
  }
  float inv = 1.f / sum;
  float4* w4 = (float4*)p;
#pragma unroll
  for (int j = 0; j < 8; ++j) {
    float4 t;
    t.x = d[4 * j + 0] * inv; t.y = d[4 * j + 1] * inv;
    t.z = d[4 * j + 2] * inv; t.w = d[4 * j + 3] * inv;
    w4[j] = t;
  }
#pragma unroll
  for (int k = 0; k < Kk; ++k) atomicAdd(&s_sum[k], d[k] * inv);
  __syncthreads();
  if (tid < Kk) atomicAdd(&asum[b * Kk + tid], s_sum[tid]);
}

// ---------------- K5: enc partials: part[s][b][k][c] ----------------
__global__ __launch_bounds__(256) void k_enc_part(const float* __restrict__ assign,
                                                  const __hip_bfloat16* __restrict__ Z,
                                                  float* __restrict__ part) {
  __shared__ float sa[128][Kk];
  int b = blockIdx.z;
  int s = blockIdx.y;
  int c = blockIdx.x * 256 + threadIdx.x;
  int tid = threadIdx.x;
  int n0 = s * 128;
  const float* ap = assign + ((size_t)b * Nn + n0) * Kk;
  for (int i = tid; i < 128 * Kk; i += 256) sa[i >> 5][i & 31] = ap[i];
  __syncthreads();
  float acc[Kk];
#pragma unroll
  for (int k = 0; k < Kk; ++k) acc[k] = 0.f;
  const __hip_bfloat16* zp = Z + ((size_t)b * Nn + n0) * Cc + c;
  for (int n = 0; n < 128; ++n) {
    float zv = __bfloat162float(zp[(size_t)n * Cc]);
    const float4* sp = (const float4*)&sa[n][0];
#pragma unroll
    for (int q = 0; q < 8; ++q) {
      float4 a4 = sp[q];
      acc[4 * q + 0] = fmaf(a4.x, zv, acc[4 * q + 0]);
      acc[4 * q + 1] = fmaf(a4.y, zv, acc[4 * q + 1]);
      acc[4 * q + 2] = fmaf(a4.z, zv, acc[4 * q + 2]);
      acc[4 * q + 3] = fmaf(a4.w, zv, acc[4 * q + 3]);
    }
  }
  float* pp = part + (((size_t)s * Bb + b) * Kk) * Cc + c;
#pragma unroll
  for (int k = 0; k < Kk; ++k) pp[(size_t)k * Cc] = acc[k];
}

// ---------------- K6: reduce partials + BN + relu -> encr[b][k][c] ----------------
__global__ __launch_bounds__(256) void k_enc_bn(const float* __restrict__ part,
                                                const float* __restrict__ asum,
                                                const float* __restrict__ cw,
                                                const float* __restrict__ bn_g,
                                                const float* __restrict__ bn_b,
                                                const float* __restrict__ bn_m,
                                                const float* __restrict__ bn_v,
                                                float* __restrict__ encr) {
  int bk = blockIdx.x;  // b*32+k
  int b = bk >> 5, k = bk & 31;
  int tid = threadIdx.x;
  float g = bn_g[k], bt = bn_b[k], mn = bn_m[k], iv = rsqrtf(bn_v[k] + 1e-5f);
  float as = asum[bk];
  for (int c = tid; c < Cc; c += 256) {
    float e = 0.f;
#pragma unroll
    for (int s = 0; s < NSPLIT; ++s)
      e += part[(((size_t)s * Bb + b) * Kk + k) * Cc + c];
    e -= as * cw[k * Cc + c];
    e = (e - mn) * (iv * g) + bt;
    e = fmaxf(e, 0.f);
    encr[((size_t)b * Kk + k) * Cc + c] = e;
  }
}

// ---------------- K7: mean over k -> encoding_feat (d_out) ----------------
__global__ void k_mean(const float* __restrict__ encr, float* __restrict__ ef) {
  int b = blockIdx.x;
  int c = threadIdx.x;  // 512
  float s = 0.f;
#pragma unroll
  for (int k = 0; k < Kk; ++k) s += encr[((size_t)b * Kk + k) * Cc + c];
  ef[b * Cc + c] = s * (1.f / 32.f);
}

// ---------------- K8: fc + sigmoid -> gamma[b][o] ----------------
__global__ void k_fc(const float* __restrict__ ef, const float* __restrict__ fcw,
                     const float* __restrict__ fcb, float* __restrict__ gamma) {
  int b = blockIdx.x;
  int o = blockIdx.y * 4 + (threadIdx.x >> 6);
  int lane = threadIdx.x & 63;
  const float* w = fcw + (size_t)o * Cc;
  const float* e = ef + b * Cc;
  float s = 0.f;
#pragma unroll
  for (int j = 0; j < 8; ++j) s += e[lane + j * 64] * w[lane + j * 64];
  for (int off = 32; off; off >>= 1) s += __shfl_down(s, off);
  if (lane == 0) gamma[b * Cc + o] = 1.f / (1.f + __expf(-(s + fcb[o])));
}

// ---------------- K9: output = relu(x * (1+gamma)) ----------------
__global__ __launch_bounds__(256) void k_out(const float* __restrict__ x,
                                             const float* __restrict__ gamma,
                                             float* __restrict__ out) {
  size_t total = (size_t)Bb * Cc * Nn / 4;
  for (size_t i = (size_t)blockIdx.x * 256 + threadIdx.x; i < total;
       i += (size_t)gridDim.x * 256) {
    float4 v = ((const float4*)x)[i];
    int bc = (int)(i >> 10);  // 1024 float4 per (b,c)
    float m = 1.f + gamma[bc];
    float4 r;
    r.x = fmaxf(v.x * m, 0.f);
    r.y = fmaxf(v.y * m, 0.f);
    r.z = fmaxf(v.z * m, 0.f);
    r.w = fmaxf(v.w * m, 0.f);
    ((float4*)out)[i] = r;
  }
}

extern "C" void kernel_launch(void* const* d_in, const int* in_sizes, int n_in,
                              void* d_out, int out_size, void* d_ws, size_t ws_size,
                              hipStream_t stream) {
  const float* x = (const float*)d_in[0];
  const float* conv_w = (const float*)d_in[1];
  const float* conv_b = (const float*)d_in[2];
  const float* codewords = (const float*)d_in[3];
  const float* scale = (const float*)d_in[4];
  const float* bn_gamma = (const float*)d_in[5];
  const float* bn_beta = (const float*)d_in[6];
  const float* bn_mean = (const float*)d_in[7];
  const float* bn_var = (const float*)d_in[8];
  const float* fc_w = (const float*)d_in[9];
  const float* fc_b = (const float*)d_in[10];

  float* ef_out = (float*)d_out;            // [16][512]
  float* out = (float*)d_out + Bb * Cc;     // [16][512][4096]

  char* ws = (char*)d_ws;
  size_t off = 0;
  float* part = (float*)(ws + off);                  // 32 MB (reuses old xT slot)
  off += (size_t)Bb * Nn * Cc * 2;
  __hip_bfloat16* z = (__hip_bfloat16*)(ws + off);   // 64 MB
  off += (size_t)Bb * Nn * Cc * 2;
  float* cross = (float*)(ws + off);                 // 8 MB (assign in-place)
  off += (size_t)Bb * Nn * Kk * 4;
  __hip_bfloat16* wbf = (__hip_bfloat16*)(ws + off);
  off += (size_t)Cc * Cc * 2;
  __hip_bfloat16* cwb = (__hip_bfloat16*)(ws + off);
  off += (size_t)Kk * Cc * 2;
  float* cwsq = (float*)(ws + off);
  off += 512;
  float* zsq = (float*)(ws + off);
  off += (size_t)Bb * Nn * 4;
  float* asum = (float*)(ws + off);
  off += (size_t)Bb * Kk * 4;
  float* encr = (float*)(ws + off);
  off += (size_t)Bb * Kk * Cc * 4;
  float* gamma = (float*)(ws + off);
  off += (size_t)Bb * Cc * 4;
  (void)ws_size; (void)n_in; (void)in_sizes; (void)out_size;

  hipMemsetAsync(asum, 0, Bb * Kk * 4, stream);

  k_castw<<<dim3(Cc * Cc / 256), dim3(256), 0, stream>>>(conv_w, wbf);
  k_cw<<<dim3(Kk), dim3(64), 0, stream>>>(codewords, cwb, cwsq);
  k_gemm_z<<<dim3((Nn / 128) * 4, Bb), dim3(256), 0, stream>>>(x, wbf, conv_b, z);
  k_cross<<<dim3(Nn / 128, Bb), dim3(256), 0, stream>>>(z, cwb, cross, zsq);
  k_softmax<<<dim3(Bb * Nn / 256), dim3(256), 0, stream>>>(cross, zsq, scale, cwsq, asum);
  k_enc_part<<<dim3(Cc / 256, NSPLIT, Bb), dim3(256), 0, stream>>>(cross, z, part);
  k_enc_bn<<<dim3(Bb * Kk), dim3(256), 0, stream>>>(part, asum, codewords, bn_gamma, bn_beta,
                                                    bn_mean, bn_var, encr);
  k_mean<<<dim3(Bb), dim3(512), 0, stream>>>(encr, ef_out);
  k_fc<<<dim3(Bb, Cc / 4), dim3(256), 0, stream>>>(ef_out, fc_w, fc_b, gamma);
  k_out<<<dim3(2048), dim3(256), 0, stream>>>(x, gamma, out);
}

// Round 3
// 213.012 us; speedup vs baseline: 1.3343x; 1.3264x over previous
//
#include <hip/hip_runtime.h>
#include <hip/hip_bf16.h>
#include <stdint.h>

#define DEV static __device__ __forceinline__

typedef __attribute__((ext_vector_type(8))) short bf16x8;
typedef __attribute__((ext_vector_type(4))) float f32x4;

DEV void async_ld16(const void* g, void* l) {
  __builtin_amdgcn_global_load_lds(
      (const __attribute__((address_space(1))) void*)g,
      (__attribute__((address_space(3))) void*)l, 16, 0, 0);
}

DEV unsigned short f2bf(float f) {
  union { __hip_bfloat16 h; unsigned short u; } c;
  c.h = __float2bfloat16(f);
  return c.u;
}

// ---------------- constants ----------------
#define Bb 16
#define Cc 512
#define Nn 4096   // H*W
#define Kk 32
#define NSPLIT 32 // n-chunks for enc partials

// ---------------- K0a: cast conv_w -> bf16 ----------------
__global__ void k_castw(const float* __restrict__ a, __hip_bfloat16* __restrict__ o) {
  int i = blockIdx.x * 256 + threadIdx.x;
  o[i] = __float2bfloat16(a[i]);
}

// ---------------- K0b: codewords -> bf16 + cw_sq ----------------
__global__ void k_cw(const float* __restrict__ cw, __hip_bfloat16* __restrict__ cwb,
                     float* __restrict__ cwsq) {
  int k = blockIdx.x, lane = threadIdx.x; // 64 lanes
  float s = 0.f;
#pragma unroll
  for (int j = 0; j < 8; ++j) {
    float v = cw[k * Cc + lane * 8 + j];
    cwb[k * Cc + lane * 8 + j] = __float2bfloat16(v);
    s += v * v;
  }
  for (int off = 32; off; off >>= 1) s += __shfl_down(s, off);
  if (lane == 0) cwsq[k] = s;
}

// ---------------- K2: z[b,n,c] = x^T . conv_w^T + bias (fused transpose-cast MFMA) ----------------
// A staging: thread owns 4c' x 4n micro-tile: 4x global_load_dwordx4 (float4 along n),
// in-register transpose, 4x ds_write_b64 to As[n][c'] (pad-36, ~4-way banks).
// Grid: c0 slow so x streams into L3 once; later c-phases hit L3.
__global__ __launch_bounds__(256) void k_gemm_z(const float* __restrict__ X,
                                                const __hip_bfloat16* __restrict__ Bw,
                                                const float* __restrict__ bias,
                                                __hip_bfloat16* __restrict__ Z) {
  constexpr int LDA = 36;  // padded row stride (shorts)
  __shared__ __align__(16) unsigned short As[128 * LDA];   // 9216 B
  __shared__ __align__(16) __hip_bfloat16 Bs[128 * 32];    // 8192 B
  const int b = blockIdx.y;
  const int n0 = (blockIdx.x & 31) * 128;
  const int c0 = (blockIdx.x >> 5) * 128;
  const int tid = threadIdx.x;
  const int lane = tid & 63, wid = tid >> 6;
  const int wr = (wid >> 1) * 64, wc = (wid & 1) * 64;
  const int cg = tid & 7;    // c'-quad 0..7
  const int ng = tid >> 3;   // n-quad 0..31
  const float* Xb = X + (size_t)b * Cc * Nn + n0 + ng * 4;
  const __hip_bfloat16* Bbp = Bw + (size_t)c0 * Cc;
  f32x4 acc[4][4] = {};
  for (int kt = 0; kt < 16; ++kt) {
    int k0 = kt * 32;
    __syncthreads();
    // ---- B staging via global_load_lds ----
#pragma unroll
    for (int j = 0; j < 2; ++j) {
      int li = tid + j * 256;
      int row = li >> 2, kc = (li & 3) * 8;
      async_ld16(Bbp + (size_t)row * Cc + k0 + kc, (char*)Bs + li * 16);
    }
    // ---- A staging: vector loads + in-register transpose ----
    float vv[4][4];
#pragma unroll
    for (int i = 0; i < 4; ++i) {
      float4 t = *(const float4*)&Xb[(size_t)(k0 + cg * 4 + i) * Nn];
      vv[i][0] = t.x; vv[i][1] = t.y; vv[i][2] = t.z; vv[i][3] = t.w;
    }
#pragma unroll
    for (int j = 0; j < 4; ++j) {
      ushort4 w;
      w.x = f2bf(vv[0][j]);
      w.y = f2bf(vv[1][j]);
      w.z = f2bf(vv[2][j]);
      w.w = f2bf(vv[3][j]);
      *(ushort4*)&As[(ng * 4 + j) * LDA + cg * 4] = w;  // As[n][c']
    }
    __syncthreads();
    // ---- fragment reads + MFMA ----
    bf16x8 af[4], bfv[4];
#pragma unroll
    for (int m = 0; m < 4; ++m) {
      int base = (wr + m * 16 + (lane & 15)) * LDA + (lane >> 4) * 8;
      union { ushort4 u2[2]; bf16x8 v8; } t;
      t.u2[0] = *(const ushort4*)&As[base];
      t.u2[1] = *(const ushort4*)&As[base + 4];
      af[m] = t.v8;
    }
#pragma unroll
    for (int nf = 0; nf < 4; ++nf)
      bfv[nf] = *(const bf16x8*)&Bs[(wc + nf * 16 + (lane & 15)) * 32 + (lane >> 4) * 8];
#pragma unroll
    for (int m = 0; m < 4; ++m)
#pragma unroll
      for (int nf = 0; nf < 4; ++nf)
        acc[m][nf] = __builtin_amdgcn_mfma_f32_16x16x32_bf16(af[m], bfv[nf], acc[m][nf], 0, 0, 0);
  }
  __hip_bfloat16* Zb = Z + ((size_t)b * Nn + n0) * Cc + c0;
#pragma unroll
  for (int nf = 0; nf < 4; ++nf) {
    int col = wc + nf * 16 + (lane & 15);
    float bv = bias[c0 + col];
#pragma unroll
    for (int m = 0; m < 4; ++m) {
#pragma unroll
      for (int r = 0; r < 4; ++r) {
        int row = wr + m * 16 + (lane >> 4) * 4 + r;
        Zb[(size_t)row * Cc + col] = __float2bfloat16(acc[m][nf][r] + bv);
      }
    }
  }
}

// ---------------- K3: cross + softmax fused -> assign[b,n,k], asum[b,k] ----------------
// MFMA acc holds cross[n,k]: rows n via (m, lane>>4, r), cols k via (nf, lane&15).
// Softmax over k = shfl_xor reduce over lane bits 0..3 (16 lanes span k with nf pair).
__global__ __launch_bounds__(256) void k_cross(const __hip_bfloat16* __restrict__ Z,
                                               const __hip_bfloat16* __restrict__ CW,
                                               const float* __restrict__ scale,
                                               const float* __restrict__ cwsq,
                                               float* __restrict__ assign,
                                               float* __restrict__ asum) {
  __shared__ __align__(16) __hip_bfloat16 As[128 * 32];
  __shared__ __align__(16) __hip_bfloat16 Bs[32 * 32];
  __shared__ float s_zsq[128];
  __shared__ float s_asum[Kk];
  int b = blockIdx.y;
  int n0 = blockIdx.x * 128;
  int tid = threadIdx.x, lane = tid & 63, wid = tid >> 6;
  if (tid < Kk) s_asum[tid] = 0.f;
  const __hip_bfloat16* Ab = Z + ((size_t)b * Nn + n0) * Cc;
  f32x4 acc[2][2] = {};
  float sq = 0.f;
  for (int kt = 0; kt < 16; ++kt) {
    int k0 = kt * 32;
    __syncthreads();
#pragma unroll
    for (int j = 0; j < 2; ++j) {
      int li = tid + j * 256;
      int row = li >> 2, kc = (li & 3) * 8;
      async_ld16(Ab + (size_t)row * Cc + k0 + kc, (char*)As + li * 16);
    }
    if (tid < 128) {
      int row = tid >> 2, kc = (tid & 3) * 8;
      async_ld16(CW + (size_t)row * Cc + k0 + kc, (char*)Bs + tid * 16);
    }
    __syncthreads();
    {  // z_sq partial from staged tile
      int row = tid >> 1, h = (tid & 1) * 16;
      const __hip_bfloat16* p = &As[row * 32 + h];
#pragma unroll
      for (int i = 0; i < 16; ++i) {
        float v = __bfloat162float(p[i]);
        sq += v * v;
      }
    }
    bf16x8 af[2], bfv[2];
#pragma unroll
    for (int m = 0; m < 2; ++m)
      af[m] = *(const bf16x8*)&As[(wid * 32 + m * 16 + (lane & 15)) * 32 + (lane >> 4) * 8];
#pragma unroll
    for (int nf = 0; nf < 2; ++nf)
      bfv[nf] = *(const bf16x8*)&Bs[(nf * 16 + (lane & 15)) * 32 + (lane >> 4) * 8];
#pragma unroll
    for (int m = 0; m < 2; ++m)
#pragma unroll
      for (int nf = 0; nf < 2; ++nf)
        acc[m][nf] = __builtin_amdgcn_mfma_f32_16x16x32_bf16(af[m], bfv[nf], acc[m][nf], 0, 0, 0);
  }
  sq += __shfl_xor(sq, 1);
  if ((tid & 1) == 0) s_zsq[tid >> 1] = sq;
  __syncthreads();
  // ---- in-register softmax over k ----
  float sc[2], cq[2];
#pragma unroll
  for (int nf = 0; nf < 2; ++nf) {
    sc[nf] = scale[nf * 16 + (lane & 15)];
    cq[nf] = cwsq[nf * 16 + (lane & 15)];
  }
  float asump0 = 0.f, asump1 = 0.f;
#pragma unroll
  for (int m = 0; m < 2; ++m) {
#pragma unroll
    for (int r = 0; r < 4; ++r) {
      int row = wid * 32 + m * 16 + (lane >> 4) * 4 + r;
      float zq = s_zsq[row];
      float v0 = sc[0] * (zq - 2.f * acc[m][0][r] + cq[0]);
      float v1 = sc[1] * (zq - 2.f * acc[m][1][r] + cq[1]);
      float mx = fmaxf(v0, v1);
#pragma unroll
      for (int off = 1; off < 16; off <<= 1) mx = fmaxf(mx, __shfl_xor(mx, off));
      float e0 = __expf(v0 - mx), e1 = __expf(v1 - mx);
      float s = e0 + e1;
#pragma unroll
      for (int off = 1; off < 16; off <<= 1) s += __shfl_xor(s, off);
      float inv = 1.f / s;
      float a0 = e0 * inv, a1 = e1 * inv;
      acc[m][0][r] = a0;
      acc[m][1][r] = a1;
      asump0 += a0;
      asump1 += a1;
    }
  }
  // sum over the 4 (lane>>4) row-groups: lanes with same lane&15 hold same cols
  asump0 += __shfl_xor(asump0, 16); asump0 += __shfl_xor(asump0, 32);
  asump1 += __shfl_xor(asump1, 16); asump1 += __shfl_xor(asump1, 32);
  if (lane < 16) {
    atomicAdd(&s_asum[lane], asump0);
    atomicAdd(&s_asum[16 + lane], asump1);
  }
  // ---- write assign ----
  float* Cb = assign + ((size_t)b * Nn + n0) * Kk;
#pragma unroll
  for (int m = 0; m < 2; ++m)
#pragma unroll
    for (int nf = 0; nf < 2; ++nf) {
      int col = nf * 16 + (lane & 15);
#pragma unroll
      for (int r = 0; r < 4; ++r) {
        int row = wid * 32 + m * 16 + (lane >> 4) * 4 + r;
        Cb[(size_t)row * Kk + col] = acc[m][nf][r];
      }
    }
  __syncthreads();
  if (tid < Kk) atomicAdd(&asum[b * Kk + tid], s_asum[tid]);
}

// ---------------- K5: enc partials: part[s][b][k][c] ----------------
__global__ __launch_bounds__(256) void k_enc_part(const float* __restrict__ assign,
                                                  const __hip_bfloat16* __restrict__ Z,
                                                  float* __restrict__ part) {
  __shared__ float sa[128][Kk];
  int b = blockIdx.z;
  int s = blockIdx.y;
  int c = blockIdx.x * 256 + threadIdx.x;
  int tid = threadIdx.x;
  int n0 = s * 128;
  const float* ap = assign + ((size_t)b * Nn + n0) * Kk;
  for (int i = tid; i < 128 * Kk; i += 256) sa[i >> 5][i & 31] = ap[i];
  __syncthreads();
  float acc[Kk];
#pragma unroll
  for (int k = 0; k < Kk; ++k) acc[k] = 0.f;
  const __hip_bfloat16* zp = Z + ((size_t)b * Nn + n0) * Cc + c;
  for (int n = 0; n < 128; ++n) {
    float zv = __bfloat162float(zp[(size_t)n * Cc]);
    const float4* sp = (const float4*)&sa[n][0];
#pragma unroll
    for (int q = 0; q < 8; ++q) {
      float4 a4 = sp[q];
      acc[4 * q + 0] = fmaf(a4.x, zv, acc[4 * q + 0]);
      acc[4 * q + 1] = fmaf(a4.y, zv, acc[4 * q + 1]);
      acc[4 * q + 2] = fmaf(a4.z, zv, acc[4 * q + 2]);
      acc[4 * q + 3] = fmaf(a4.w, zv, acc[4 * q + 3]);
    }
  }
  float* pp = part + (((size_t)s * Bb + b) * Kk) * Cc + c;
#pragma unroll
  for (int k = 0; k < Kk; ++k) pp[(size_t)k * Cc] = acc[k];
}

// ---------------- K6: reduce partials + BN + relu + mean-atomic -> ef ----------------
__global__ __launch_bounds__(256) void k_enc_bn(const float* __restrict__ part,
                                                const float* __restrict__ asum,
                                                const float* __restrict__ cw,
                                                const float* __restrict__ bn_g,
                                                const float* __restrict__ bn_b,
                                                const float* __restrict__ bn_m,
                                                const float* __restrict__ bn_v,
                                                float* __restrict__ ef) {
  int bk = blockIdx.x;  // b*32+k
  int b = bk >> 5, k = bk & 31;
  int tid = threadIdx.x;
  float g = bn_g[k], bt = bn_b[k], mn = bn_m[k], iv = rsqrtf(bn_v[k] + 1e-5f);
  float as = asum[bk];
  for (int c = tid; c < Cc; c += 256) {
    float e = 0.f;
#pragma unroll
    for (int s = 0; s < NSPLIT; ++s)
      e += part[(((size_t)s * Bb + b) * Kk + k) * Cc + c];
    e -= as * cw[k * Cc + c];
    e = (e - mn) * (iv * g) + bt;
    e = fmaxf(e, 0.f);
    atomicAdd(&ef[b * Cc + c], e * (1.f / 32.f));
  }
}

// ---------------- K8: fc + sigmoid -> gamma[b][o] ----------------
__global__ void k_fc(const float* __restrict__ ef, const float* __restrict__ fcw,
                     const float* __restrict__ fcb, float* __restrict__ gamma) {
  int b = blockIdx.x;
  int o = blockIdx.y * 4 + (threadIdx.x >> 6);
  int lane = threadIdx.x & 63;
  const float* w = fcw + (size_t)o * Cc;
  const float* e = ef + b * Cc;
  float s = 0.f;
#pragma unroll
  for (int j = 0; j < 8; ++j) s += e[lane + j * 64] * w[lane + j * 64];
  for (int off = 32; off; off >>= 1) s += __shfl_down(s, off);
  if (lane == 0) gamma[b * Cc + o] = 1.f / (1.f + __expf(-(s + fcb[o])));
}

// ---------------- K9: output = relu(x * (1+gamma)), one block per (b,c) ----------------
__global__ __launch_bounds__(256) void k_out(const float* __restrict__ x,
                                             const float* __restrict__ gamma,
                                             float* __restrict__ out) {
  int bc = blockIdx.x;
  float m = 1.f + gamma[bc];
  size_t base = (size_t)bc * (Nn / 4);
  const float4* xp = (const float4*)x + base;
  float4* op = (float4*)out + base;
#pragma unroll
  for (int j = 0; j < 4; ++j) {
    int i = j * 256 + threadIdx.x;
    float4 v = xp[i];
    float4 r;
    r.x = fmaxf(v.x * m, 0.f);
    r.y = fmaxf(v.y * m, 0.f);
    r.z = fmaxf(v.z * m, 0.f);
    r.w = fmaxf(v.w * m, 0.f);
    op[i] = r;
  }
}

extern "C" void kernel_launch(void* const* d_in, const int* in_sizes, int n_in,
                              void* d_out, int out_size, void* d_ws, size_t ws_size,
                              hipStream_t stream) {
  const float* x = (const float*)d_in[0];
  const float* conv_w = (const float*)d_in[1];
  const float* conv_b = (const float*)d_in[2];
  const float* codewords = (const float*)d_in[3];
  const float* scale = (const float*)d_in[4];
  const float* bn_gamma = (const float*)d_in[5];
  const float* bn_beta = (const float*)d_in[6];
  const float* bn_mean = (const float*)d_in[7];
  const float* bn_var = (const float*)d_in[8];
  const float* fc_w = (const float*)d_in[9];
  const float* fc_b = (const float*)d_in[10];

  float* ef_out = (float*)d_out;            // [16][512]
  float* out = (float*)d_out + Bb * Cc;     // [16][512][4096]

  char* ws = (char*)d_ws;
  size_t off = 0;
  float* part = (float*)(ws + off);                  // 32 MB
  off += (size_t)NSPLIT * Bb * Kk * Cc * 4;
  __hip_bfloat16* z = (__hip_bfloat16*)(ws + off);   // 64 MB
  off += (size_t)Bb * Nn * Cc * 2;
  float* assign = (float*)(ws + off);                // 8 MB
  off += (size_t)Bb * Nn * Kk * 4;
  __hip_bfloat16* wbf = (__hip_bfloat16*)(ws + off);
  off += (size_t)Cc * Cc * 2;
  __hip_bfloat16* cwb = (__hip_bfloat16*)(ws + off);
  off += (size_t)Kk * Cc * 2;
  float* cwsq = (float*)(ws + off);
  off += 512;
  float* asum = (float*)(ws + off);
  off += (size_t)Bb * Kk * 4;
  float* gamma = (float*)(ws + off);
  off += (size_t)Bb * Cc * 4;
  (void)ws_size; (void)n_in; (void)in_sizes; (void)out_size;

  hipMemsetAsync(asum, 0, Bb * Kk * 4, stream);
  hipMemsetAsync(ef_out, 0, Bb * Cc * 4, stream);  // mean accumulated via atomics

  k_castw<<<dim3(Cc * Cc / 256), dim3(256), 0, stream>>>(conv_w, wbf);
  k_cw<<<dim3(Kk), dim3(64), 0, stream>>>(codewords, cwb, cwsq);
  k_gemm_z<<<dim3((Nn / 128) * 4, Bb), dim3(256), 0, stream>>>(x, wbf, conv_b, z);
  k_cross<<<dim3(Nn / 128, Bb), dim3(256), 0, stream>>>(z, cwb, scale, cwsq, assign, asum);
  k_enc_part<<<dim3(Cc / 256, NSPLIT, Bb), dim3(256), 0, stream>>>(assign, z, part);
  k_enc_bn<<<dim3(Bb * Kk), dim3(256), 0, stream>>>(part, asum, codewords, bn_gamma, bn_beta,
                                                    bn_mean, bn_var, ef_out);
  k_fc<<<dim3(Bb, Cc / 4), dim3(256), 0, stream>>>(ef_out, fc_w, fc_b, gamma);
  k_out<<<dim3(Bb * Cc), dim3(256), 0, stream>>>(x, gamma, out);
}

// Round 4
// 185.791 us; speedup vs baseline: 1.5298x; 1.1465x over previous
//
#include <hip/hip_runtime.h>
#include <hip/hip_bf16.h>
#include <stdint.h>

#define DEV static __device__ __forceinline__

typedef __attribute__((ext_vector_type(8))) short bf16x8;
typedef __attribute__((ext_vector_type(4))) float f32x4;

DEV void async_ld16(const void* g, void* l) {
  __builtin_amdgcn_global_load_lds(
      (const __attribute__((address_space(1))) void*)g,
      (__attribute__((address_space(3))) void*)l, 16, 0, 0);
}

DEV unsigned short f2bf(float f) {
  union { __hip_bfloat16 h; unsigned short u; } c;
  c.h = __float2bfloat16(f);
  return c.u;
}

// ---------------- constants ----------------
#define Bb 16
#define Cc 512
#define Nn 4096   // H*W
#define Kk 32
#define NSPLIT 32 // n-chunks for enc partials

// ---------------- K0a: cast conv_w -> bf16 ----------------
__global__ void k_castw(const float* __restrict__ a, __hip_bfloat16* __restrict__ o) {
  int i = blockIdx.x * 256 + threadIdx.x;
  o[i] = __float2bfloat16(a[i]);
}

// ---------------- K0b: codewords -> bf16 + cw_sq ----------------
__global__ void k_cw(const float* __restrict__ cw, __hip_bfloat16* __restrict__ cwb,
                     float* __restrict__ cwsq) {
  int k = blockIdx.x, lane = threadIdx.x; // 64 lanes
  float s = 0.f;
#pragma unroll
  for (int j = 0; j < 8; ++j) {
    float v = cw[k * Cc + lane * 8 + j];
    cwb[k * Cc + lane * 8 + j] = __float2bfloat16(v);
    s += v * v;
  }
  for (int off = 32; off; off >>= 1) s += __shfl_down(s, off);
  if (lane == 0) cwsq[k] = s;
}

// ---------------- K2: z[b,n,c] = x^T . conv_w^T + bias ----------------
// 2-phase double-buffered pipeline (1 barrier / K-step):
//   ds_write A(t) [waits only A-regs] ; gload_lds B(t) ; barrier [drains B(t)];
//   issue A(t+1) regs  <- latency hidden under frag-reads + MFMA(t);
//   frag reads + MFMA(t).
// A staging: thread (cg=tid>>5, ng=tid&31) loads 4 rows c=k0+cg*4+i, float4 at
// n=4*ng -> per-wave 2x512B contiguous; in-reg transpose; ds_write_b64 to
// As[n][c'] (pad-36; frag reads are conflict-free 4-way minimum).
__global__ __launch_bounds__(256) void k_gemm_z(const float* __restrict__ X,
                                                const __hip_bfloat16* __restrict__ Bw,
                                                const float* __restrict__ bias,
                                                __hip_bfloat16* __restrict__ Z) {
  constexpr int LDA = 36;                 // padded row stride (shorts)
  constexpr int AE = 128 * LDA;           // elems per A buffer
  constexpr int BE = 128 * 32;            // elems per B buffer
  __shared__ __align__(16) unsigned short As[2 * AE];   // 18432 B
  __shared__ __align__(16) __hip_bfloat16 Bs[2 * BE];   // 16384 B
  const int b = blockIdx.y;
  const int n0 = (blockIdx.x & 31) * 128;
  const int c0 = (blockIdx.x >> 5) * 128;
  const int tid = threadIdx.x;
  const int lane = tid & 63, wid = tid >> 6;
  const int wr = (wid >> 1) * 64, wc = (wid & 1) * 64;
  const int cg = tid >> 5;   // c-quad 0..7
  const int ng = tid & 31;   // n-quad 0..31
  const float* Xb = X + (size_t)b * Cc * Nn + n0 + ng * 4;
  const __hip_bfloat16* Bbp = Bw + (size_t)c0 * Cc;
  f32x4 acc[4][4] = {};
  float4 av[4];
  // prologue: issue A(0)
#pragma unroll
  for (int i = 0; i < 4; ++i)
    av[i] = *(const float4*)&Xb[(size_t)(cg * 4 + i) * Nn];
  int cur = 0;
  for (int kt = 0; kt < 16; ++kt) {
    // ---- phase 1: commit A(kt) to LDS (implicit vmcnt wait on av only) ----
    unsigned short* Aw = As + cur * AE;
#pragma unroll
    for (int j = 0; j < 4; ++j) {
      ushort4 w;
      w.x = f2bf(av[0][j]);
      w.y = f2bf(av[1][j]);
      w.z = f2bf(av[2][j]);
      w.w = f2bf(av[3][j]);
      *(ushort4*)&Aw[(ng * 4 + j) * LDA + cg * 4] = w;  // As[n][c']
    }
    // ---- B staging via global_load_lds ----
    char* Bwr = (char*)(Bs + cur * BE);
#pragma unroll
    for (int j = 0; j < 2; ++j) {
      int li = tid + j * 256;
      int row = li >> 2, kc = (li & 3) * 8;
      async_ld16(Bbp + (size_t)row * Cc + kt * 32 + kc, Bwr + li * 16);
    }
    __syncthreads();  // drains B(kt); A(kt+1) not yet issued
    // ---- prefetch A(kt+1): overlaps frag reads + MFMA below ----
    if (kt < 15) {
#pragma unroll
      for (int i = 0; i < 4; ++i)
        av[i] = *(const float4*)&Xb[(size_t)((kt + 1) * 32 + cg * 4 + i) * Nn];
    }
    // ---- fragment reads + MFMA ----
    const unsigned short* Ar = As + cur * AE;
    const __hip_bfloat16* Br = Bs + cur * BE;
    bf16x8 af[4], bfv[4];
#pragma unroll
    for (int m = 0; m < 4; ++m) {
      int base = (wr + m * 16 + (lane & 15)) * LDA + (lane >> 4) * 8;
      union { ushort4 u2[2]; bf16x8 v8; } t;
      t.u2[0] = *(const ushort4*)&Ar[base];
      t.u2[1] = *(const ushort4*)&Ar[base + 4];
      af[m] = t.v8;
    }
#pragma unroll
    for (int nf = 0; nf < 4; ++nf)
      bfv[nf] = *(const bf16x8*)&Br[(wc + nf * 16 + (lane & 15)) * 32 + (lane >> 4) * 8];
#pragma unroll
    for (int m = 0; m < 4; ++m)
#pragma unroll
      for (int nf = 0; nf < 4; ++nf)
        acc[m][nf] = __builtin_amdgcn_mfma_f32_16x16x32_bf16(af[m], bfv[nf], acc[m][nf], 0, 0, 0);
    cur ^= 1;
  }
  __hip_bfloat16* Zb = Z + ((size_t)b * Nn + n0) * Cc + c0;
#pragma unroll
  for (int nf = 0; nf < 4; ++nf) {
    int col = wc + nf * 16 + (lane & 15);
    float bv = bias[c0 + col];
#pragma unroll
    for (int m = 0; m < 4; ++m) {
#pragma unroll
      for (int r = 0; r < 4; ++r) {
        int row = wr + m * 16 + (lane >> 4) * 4 + r;
        Zb[(size_t)row * Cc + col] = __float2bfloat16(acc[m][nf][r] + bv);
      }
    }
  }
}

// ---------------- K3: cross + softmax fused -> assign[b,n,k], asum[b,k] ----------------
__global__ __launch_bounds__(256) void k_cross(const __hip_bfloat16* __restrict__ Z,
                                               const __hip_bfloat16* __restrict__ CW,
                                               const float* __restrict__ scale,
                                               const float* __restrict__ cwsq,
                                               float* __restrict__ assign,
                                               float* __restrict__ asum) {
  __shared__ __align__(16) __hip_bfloat16 As[128 * 32];
  __shared__ __align__(16) __hip_bfloat16 Bs[32 * 32];
  __shared__ float s_zsq[128];
  __shared__ float s_asum[Kk];
  int b = blockIdx.y;
  int n0 = blockIdx.x * 128;
  int tid = threadIdx.x, lane = tid & 63, wid = tid >> 6;
  if (tid < Kk) s_asum[tid] = 0.f;
  const __hip_bfloat16* Ab = Z + ((size_t)b * Nn + n0) * Cc;
  f32x4 acc[2][2] = {};
  float sq = 0.f;
  for (int kt = 0; kt < 16; ++kt) {
    int k0 = kt * 32;
    __syncthreads();
#pragma unroll
    for (int j = 0; j < 2; ++j) {
      int li = tid + j * 256;
      int row = li >> 2, kc = (li & 3) * 8;
      async_ld16(Ab + (size_t)row * Cc + k0 + kc, (char*)As + li * 16);
    }
    if (tid < 128) {
      int row = tid >> 2, kc = (tid & 3) * 8;
      async_ld16(CW + (size_t)row * Cc + k0 + kc, (char*)Bs + tid * 16);
    }
    __syncthreads();
    {  // z_sq partial from staged tile
      int row = tid >> 1, h = (tid & 1) * 16;
      const __hip_bfloat16* p = &As[row * 32 + h];
#pragma unroll
      for (int i = 0; i < 16; ++i) {
        float v = __bfloat162float(p[i]);
        sq += v * v;
      }
    }
    bf16x8 af[2], bfv[2];
#pragma unroll
    for (int m = 0; m < 2; ++m)
      af[m] = *(const bf16x8*)&As[(wid * 32 + m * 16 + (lane & 15)) * 32 + (lane >> 4) * 8];
#pragma unroll
    for (int nf = 0; nf < 2; ++nf)
      bfv[nf] = *(const bf16x8*)&Bs[(nf * 16 + (lane & 15)) * 32 + (lane >> 4) * 8];
#pragma unroll
    for (int m = 0; m < 2; ++m)
#pragma unroll
      for (int nf = 0; nf < 2; ++nf)
        acc[m][nf] = __builtin_amdgcn_mfma_f32_16x16x32_bf16(af[m], bfv[nf], acc[m][nf], 0, 0, 0);
  }
  sq += __shfl_xor(sq, 1);
  if ((tid & 1) == 0) s_zsq[tid >> 1] = sq;
  __syncthreads();
  // ---- in-register softmax over k ----
  float sc[2], cq[2];
#pragma unroll
  for (int nf = 0; nf < 2; ++nf) {
    sc[nf] = scale[nf * 16 + (lane & 15)];
    cq[nf] = cwsq[nf * 16 + (lane & 15)];
  }
  float asump0 = 0.f, asump1 = 0.f;
#pragma unroll
  for (int m = 0; m < 2; ++m) {
#pragma unroll
    for (int r = 0; r < 4; ++r) {
      int row = wid * 32 + m * 16 + (lane >> 4) * 4 + r;
      float zq = s_zsq[row];
      float v0 = sc[0] * (zq - 2.f * acc[m][0][r] + cq[0]);
      float v1 = sc[1] * (zq - 2.f * acc[m][1][r] + cq[1]);
      float mx = fmaxf(v0, v1);
#pragma unroll
      for (int off = 1; off < 16; off <<= 1) mx = fmaxf(mx, __shfl_xor(mx, off));
      float e0 = __expf(v0 - mx), e1 = __expf(v1 - mx);
      float s = e0 + e1;
#pragma unroll
      for (int off = 1; off < 16; off <<= 1) s += __shfl_xor(s, off);
      float inv = 1.f / s;
      float a0 = e0 * inv, a1 = e1 * inv;
      acc[m][0][r] = a0;
      acc[m][1][r] = a1;
      asump0 += a0;
      asump1 += a1;
    }
  }
  asump0 += __shfl_xor(asump0, 16); asump0 += __shfl_xor(asump0, 32);
  asump1 += __shfl_xor(asump1, 16); asump1 += __shfl_xor(asump1, 32);
  if (lane < 16) {
    atomicAdd(&s_asum[lane], asump0);
    atomicAdd(&s_asum[16 + lane], asump1);
  }
  float* Cb = assign + ((size_t)b * Nn + n0) * Kk;
#pragma unroll
  for (int m = 0; m < 2; ++m)
#pragma unroll
    for (int nf = 0; nf < 2; ++nf) {
      int col = nf * 16 + (lane & 15);
#pragma unroll
      for (int r = 0; r < 4; ++r) {
        int row = wid * 32 + m * 16 + (lane >> 4) * 4 + r;
        Cb[(size_t)row * Kk + col] = acc[m][nf][r];
      }
    }
  __syncthreads();
  if (tid < Kk) atomicAdd(&asum[b * Kk + tid], s_asum[tid]);
}

// ---------------- K5: enc partials: part[s][b][k][c] ----------------
__global__ __launch_bounds__(256) void k_enc_part(const float* __restrict__ assign,
                                                  const __hip_bfloat16* __restrict__ Z,
                                                  float* __restrict__ part) {
  __shared__ float sa[128][Kk];
  int b = blockIdx.z;
  int s = blockIdx.y;
  int c = blockIdx.x * 256 + threadIdx.x;
  int tid = threadIdx.x;
  int n0 = s * 128;
  const float* ap = assign + ((size_t)b * Nn + n0) * Kk;
  for (int i = tid; i < 128 * Kk; i += 256) sa[i >> 5][i & 31] = ap[i];
  __syncthreads();
  float acc[Kk];
#pragma unroll
  for (int k = 0; k < Kk; ++k) acc[k] = 0.f;
  const __hip_bfloat16* zp = Z + ((size_t)b * Nn + n0) * Cc + c;
  for (int n = 0; n < 128; ++n) {
    float zv = __bfloat162float(zp[(size_t)n * Cc]);
    const float4* sp = (const float4*)&sa[n][0];
#pragma unroll
    for (int q = 0; q < 8; ++q) {
      float4 a4 = sp[q];
      acc[4 * q + 0] = fmaf(a4.x, zv, acc[4 * q + 0]);
      acc[4 * q + 1] = fmaf(a4.y, zv, acc[4 * q + 1]);
      acc[4 * q + 2] = fmaf(a4.z, zv, acc[4 * q + 2]);
      acc[4 * q + 3] = fmaf(a4.w, zv, acc[4 * q + 3]);
    }
  }
  float* pp = part + (((size_t)s * Bb + b) * Kk) * Cc + c;
#pragma unroll
  for (int k = 0; k < Kk; ++k) pp[(size_t)k * Cc] = acc[k];
}

// ---------------- K6: reduce partials + BN + relu + mean-atomic -> ef ----------------
__global__ __launch_bounds__(256) void k_enc_bn(const float* __restrict__ part,
                                                const float* __restrict__ asum,
                                                const float* __restrict__ cw,
                                                const float* __restrict__ bn_g,
                                                const float* __restrict__ bn_b,
                                                const float* __restrict__ bn_m,
                                                const float* __restrict__ bn_v,
                                                float* __restrict__ ef) {
  int bk = blockIdx.x;  // b*32+k
  int b = bk >> 5, k = bk & 31;
  int tid = threadIdx.x;
  float g = bn_g[k], bt = bn_b[k], mn = bn_m[k], iv = rsqrtf(bn_v[k] + 1e-5f);
  float as = asum[bk];
  for (int c = tid; c < Cc; c += 256) {
    float e = 0.f;
#pragma unroll
    for (int s = 0; s < NSPLIT; ++s)
      e += part[(((size_t)s * Bb + b) * Kk + k) * Cc + c];
    e -= as * cw[k * Cc + c];
    e = (e - mn) * (iv * g) + bt;
    e = fmaxf(e, 0.f);
    atomicAdd(&ef[b * Cc + c], e * (1.f / 32.f));
  }
}

// ---------------- K8: fc + sigmoid -> gamma[b][o] ----------------
__global__ void k_fc(const float* __restrict__ ef, const float* __restrict__ fcw,
                     const float* __restrict__ fcb, float* __restrict__ gamma) {
  int b = blockIdx.x;
  int o = blockIdx.y * 4 + (threadIdx.x >> 6);
  int lane = threadIdx.x & 63;
  const float* w = fcw + (size_t)o * Cc;
  const float* e = ef + b * Cc;
  float s = 0.f;
#pragma unroll
  for (int j = 0; j < 8; ++j) s += e[lane + j * 64] * w[lane + j * 64];
  for (int off = 32; off; off >>= 1) s += __shfl_down(s, off);
  if (lane == 0) gamma[b * Cc + o] = 1.f / (1.f + __expf(-(s + fcb[o])));
}

// ---------------- K9: output = relu(x * (1+gamma)), one block per (b,c) ----------------
__global__ __launch_bounds__(256) void k_out(const float* __restrict__ x,
                                             const float* __restrict__ gamma,
                                             float* __restrict__ out) {
  int bc = blockIdx.x;
  float m = 1.f + gamma[bc];
  size_t base = (size_t)bc * (Nn / 4);
  const float4* xp = (const float4*)x + base;
  float4* op = (float4*)out + base;
#pragma unroll
  for (int j = 0; j < 4; ++j) {
    int i = j * 256 + threadIdx.x;
    float4 v = xp[i];
    float4 r;
    r.x = fmaxf(v.x * m, 0.f);
    r.y = fmaxf(v.y * m, 0.f);
    r.z = fmaxf(v.z * m, 0.f);
    r.w = fmaxf(v.w * m, 0.f);
    op[i] = r;
  }
}

extern "C" void kernel_launch(void* const* d_in, const int* in_sizes, int n_in,
                              void* d_out, int out_size, void* d_ws, size_t ws_size,
                              hipStream_t stream) {
  const float* x = (const float*)d_in[0];
  const float* conv_w = (const float*)d_in[1];
  const float* conv_b = (const float*)d_in[2];
  const float* codewords = (const float*)d_in[3];
  const float* scale = (const float*)d_in[4];
  const float* bn_gamma = (const float*)d_in[5];
  const float* bn_beta = (const float*)d_in[6];
  const float* bn_mean = (const float*)d_in[7];
  const float* bn_var = (const float*)d_in[8];
  const float* fc_w = (const float*)d_in[9];
  const float* fc_b = (const float*)d_in[10];

  float* ef_out = (float*)d_out;            // [16][512]
  float* out = (float*)d_out + Bb * Cc;     // [16][512][4096]

  char* ws = (char*)d_ws;
  size_t off = 0;
  float* part = (float*)(ws + off);                  // 32 MB
  off += (size_t)NSPLIT * Bb * Kk * Cc * 4;
  __hip_bfloat16* z = (__hip_bfloat16*)(ws + off);   // 64 MB
  off += (size_t)Bb * Nn * Cc * 2;
  float* assign = (float*)(ws + off);                // 8 MB
  off += (size_t)Bb * Nn * Kk * 4;
  __hip_bfloat16* wbf = (__hip_bfloat16*)(ws + off);
  off += (size_t)Cc * Cc * 2;
  __hip_bfloat16* cwb = (__hip_bfloat16*)(ws + off);
  off += (size_t)Kk * Cc * 2;
  float* cwsq = (float*)(ws + off);
  off += 512;
  float* asum = (float*)(ws + off);
  off += (size_t)Bb * Kk * 4;
  float* gamma = (float*)(ws + off);
  off += (size_t)Bb * Cc * 4;
  (void)ws_size; (void)n_in; (void)in_sizes; (void)out_size;

  hipMemsetAsync(asum, 0, Bb * Kk * 4, stream);
  hipMemsetAsync(ef_out, 0, Bb * Cc * 4, stream);  // mean accumulated via atomics

  k_castw<<<dim3(Cc * Cc / 256), dim3(256), 0, stream>>>(conv_w, wbf);
  k_cw<<<dim3(Kk), dim3(64), 0, stream>>>(codewords, cwb, cwsq);
  k_gemm_z<<<dim3((Nn / 128) * 4, Bb), dim3(256), 0, stream>>>(x, wbf, conv_b, z);
  k_cross<<<dim3(Nn / 128, Bb), dim3(256), 0, stream>>>(z, cwb, scale, cwsq, assign, asum);
  k_enc_part<<<dim3(Cc / 256, NSPLIT, Bb), dim3(256), 0, stream>>>(assign, z, part);
  k_enc_bn<<<dim3(Bb * Kk), dim3(256), 0, stream>>>(part, asum, codewords, bn_gamma, bn_beta,
                                                    bn_mean, bn_var, ef_out);
  k_fc<<<dim3(Bb, Cc / 4), dim3(256), 0, stream>>>(ef_out, fc_w, fc_b, gamma);
  k_out<<<dim3(Bb * Cc), dim3(256), 0, stream>>>(x, gamma, out);
}